// Round 1
// baseline (256.352 us; speedup 1.0000x reference)
//
#include <hip/hip_runtime.h>
#include <cstdint>
#include <cstddef>

typedef _Float16 f16;
typedef f16 f16x8 __attribute__((ext_vector_type(8)));
typedef f16 f16x4 __attribute__((ext_vector_type(4)));
typedef float f32x4 __attribute__((ext_vector_type(4)));

#define SEQ 4096
#define DH 128
#define QKV_LD 384   // row stride of qkv (3*DH)

// ---------------- W fp32 -> fp16 ----------------
__global__ __launch_bounds__(256) void cvt_w_kernel(const float4* __restrict__ W,
                                                    f16x4* __restrict__ Wh) {
  int i = blockIdx.x * 256 + threadIdx.x;   // 384*4096/4 = 393216 float4
  float4 v = W[i];
  f16x4 h; h[0] = (f16)v.x; h[1] = (f16)v.y; h[2] = (f16)v.z; h[3] = (f16)v.w;
  Wh[i] = h;
}

// ---------------- QKV GEMM: qkv[i][j] = sum_k x[i][k]*W[j][k] + b[j] ----------------
// BM=128, BN=128, BK=64. 4 waves in 2x2, each wave 64x64 (4x4 MFMA frags).
__global__ __launch_bounds__(256) void gemm_qkv(const float* __restrict__ x,
                                                const f16* __restrict__ Wh,
                                                const float* __restrict__ bias,
                                                f16* __restrict__ qkv,
                                                f16* __restrict__ Vt) {
  __shared__ f16 Ax[128][72];  // +8 halves pad; row stride 144B = 9*16B (aligned, 2-way bank only)
  __shared__ f16 Bx[128][72];
  const int m0 = blockIdx.x * 128;
  const int n0 = blockIdx.y * 128;
  const int tid = threadIdx.x;
  const int lane = tid & 63, wave = tid >> 6;
  const int wr = (wave >> 1) * 64, wc = (wave & 1) * 64;
  const int l15 = lane & 15, quad = lane >> 4;

  f32x4 acc[4][4] = {};  // [mt][nt]

  for (int kt = 0; kt < SEQ; kt += 64) {
    // stage A: x[m0..+128][kt..+64] fp32 -> f16. 2048 float4 chunks / 256 thr
#pragma unroll
    for (int r = 0; r < 8; ++r) {
      int c = tid + r * 256;
      int row = c >> 4, col = (c & 15) * 4;
      float4 v = *(const float4*)&x[(size_t)(m0 + row) * SEQ + kt + col];
      f16x4 h; h[0] = (f16)v.x; h[1] = (f16)v.y; h[2] = (f16)v.z; h[3] = (f16)v.w;
      *(f16x4*)&Ax[row][col] = h;
    }
    // stage B: Wh[n0..+128][kt..+64] f16. 1024 f16x8 chunks / 256 thr
#pragma unroll
    for (int r = 0; r < 4; ++r) {
      int c = tid + r * 256;
      int row = c >> 3, col = (c & 7) * 8;
      *(f16x8*)&Bx[row][col] = *(const f16x8*)&Wh[(size_t)(n0 + row) * SEQ + kt + col];
    }
    __syncthreads();
#pragma unroll
    for (int ks = 0; ks < 2; ++ks) {
      f16x8 a[4], bb[4];
#pragma unroll
      for (int t = 0; t < 4; ++t) {
        a[t]  = *(const f16x8*)&Ax[wr + t * 16 + l15][ks * 32 + quad * 8];
        bb[t] = *(const f16x8*)&Bx[wc + t * 16 + l15][ks * 32 + quad * 8];
      }
#pragma unroll
      for (int mt = 0; mt < 4; ++mt)
#pragma unroll
        for (int nt = 0; nt < 4; ++nt)
          acc[mt][nt] = __builtin_amdgcn_mfma_f32_16x16x32_f16(a[mt], bb[nt], acc[mt][nt], 0, 0, 0);
    }
    __syncthreads();
  }

  // epilogue: C row = quad*4+rr, col = l15 (within 16-tile)
#pragma unroll
  for (int mt = 0; mt < 4; ++mt) {
#pragma unroll
    for (int nt = 0; nt < 4; ++nt) {
      int col = n0 + wc + nt * 16 + l15;
      float bv = bias[col];
      int rowbase = m0 + wr + mt * 16 + quad * 4;
      f16 hv[4];
#pragma unroll
      for (int rr = 0; rr < 4; ++rr) {
        float v = acc[mt][nt][rr] + bv;
        hv[rr] = (f16)v;
        qkv[(size_t)(rowbase + rr) * QKV_LD + col] = hv[rr];
      }
      if (n0 == 256) {  // V columns: also write V^T [128][4096], 4 consecutive rows -> 8B store
        f16x4 pk; pk[0] = hv[0]; pk[1] = hv[1]; pk[2] = hv[2]; pk[3] = hv[3];
        *(f16x4*)&Vt[(size_t)(col - 256) * SEQ + rowbase] = pk;
      }
    }
  }
}

// ---------------- Flash attention partial over a KV split ----------------
// block: 4 waves x 32 q-rows = 128 rows; KV range = split*512..+512, tiles of 64 keys.
#define NSPLIT 8
#define KVRANGE (SEQ / NSPLIT)   // 512

__global__ __launch_bounds__(256) void attn_partial(const f16* __restrict__ qkv,
                                                    const f16* __restrict__ Vt,
                                                    float* __restrict__ Op,
                                                    float* __restrict__ ml) {
  __shared__ f16 Ks[64][136];     // 64 keys x 128 d (+8 pad)
  __shared__ f16 Vs[128][72];     // V^T tile: 128 d x 64 keys (+8 pad)
  __shared__ f16 Ps[4][32][72];   // per-wave P: 32 rows x 64 cols (+8 pad)

  const int q0 = blockIdx.x * 128;
  const int split = blockIdx.y;
  const int kv0 = split * KVRANGE;
  const int tid = threadIdx.x;
  const int lane = tid & 63, wave = tid >> 6;
  const int l15 = lane & 15, quad = lane >> 4;
  const int mbase = q0 + wave * 32;

  // Q fragments: 2 m-tiles x 4 k-steps, A-layout: lane holds Q[mbase+mt*16+l15][ks*32+quad*8 ..+8]
  f16x8 qf[2][4];
#pragma unroll
  for (int mt = 0; mt < 2; ++mt)
#pragma unroll
    for (int ks = 0; ks < 4; ++ks)
      qf[mt][ks] = *(const f16x8*)&qkv[(size_t)(mbase + mt * 16 + l15) * QKV_LD + ks * 32 + quad * 8];

  f32x4 oacc[2][8] = {};
  float mrow[2][4], lrow[2][4];
#pragma unroll
  for (int mt = 0; mt < 2; ++mt)
#pragma unroll
    for (int rr = 0; rr < 4; ++rr) { mrow[mt][rr] = -1e30f; lrow[mt][rr] = 0.f; }

  for (int it = 0; it < KVRANGE / 64; ++it) {
    const int k0 = kv0 + it * 64;
    // stage K tile: qkv rows k0..+64, cols 128..256 -> Ks. 1024 f16x8 / 256 thr
#pragma unroll
    for (int r = 0; r < 4; ++r) {
      int c = tid + r * 256;
      int row = c >> 4, col = (c & 15) * 8;
      *(f16x8*)&Ks[row][col] = *(const f16x8*)&qkv[(size_t)(k0 + row) * QKV_LD + DH + col];
    }
    // stage V^T tile: Vt[d][k0..+64] -> Vs. 1024 f16x8 / 256 thr
#pragma unroll
    for (int r = 0; r < 4; ++r) {
      int c = tid + r * 256;
      int row = c >> 3, col = (c & 7) * 8;
      *(f16x8*)&Vs[row][col] = *(const f16x8*)&Vt[(size_t)row * SEQ + k0 + col];
    }
    __syncthreads();

    // S = Q K^T for this wave's 32 rows x 64 keys
    f32x4 s[2][4] = {};
#pragma unroll
    for (int ks = 0; ks < 4; ++ks) {
      f16x8 kf[4];
#pragma unroll
      for (int nt = 0; nt < 4; ++nt)
        kf[nt] = *(const f16x8*)&Ks[nt * 16 + l15][ks * 32 + quad * 8];
#pragma unroll
      for (int mt = 0; mt < 2; ++mt)
#pragma unroll
        for (int nt = 0; nt < 4; ++nt)
          s[mt][nt] = __builtin_amdgcn_mfma_f32_16x16x32_f16(qf[mt][ks], kf[nt], s[mt][nt], 0, 0, 0);
    }

    // online softmax (C-layout: row = quad*4+rr, col = nt*16+l15)
#pragma unroll
    for (int mt = 0; mt < 2; ++mt) {
      float mnew[4], al[4];
#pragma unroll
      for (int rr = 0; rr < 4; ++rr) {
        float v = s[mt][0][rr];
#pragma unroll
        for (int nt = 1; nt < 4; ++nt) v = fmaxf(v, s[mt][nt][rr]);
        for (int off = 1; off < 16; off <<= 1) v = fmaxf(v, __shfl_xor(v, off));
        mnew[rr] = fmaxf(mrow[mt][rr], v);
        al[rr] = __expf(mrow[mt][rr] - mnew[rr]);
        mrow[mt][rr] = mnew[rr];
      }
      float ls[4] = {0.f, 0.f, 0.f, 0.f};
#pragma unroll
      for (int nt = 0; nt < 4; ++nt)
#pragma unroll
        for (int rr = 0; rr < 4; ++rr) {
          float p = __expf(s[mt][nt][rr] - mnew[rr]);
          ls[rr] += p;
          Ps[wave][mt * 16 + quad * 4 + rr][nt * 16 + l15] = (f16)p;
        }
#pragma unroll
      for (int rr = 0; rr < 4; ++rr) {
        float t = ls[rr];
        for (int off = 1; off < 16; off <<= 1) t += __shfl_xor(t, off);
        lrow[mt][rr] = lrow[mt][rr] * al[rr] + t;
      }
#pragma unroll
      for (int dt = 0; dt < 8; ++dt)
#pragma unroll
        for (int rr = 0; rr < 4; ++rr)
          oacc[mt][dt][rr] *= al[rr];
    }

    // PV: O[m][d] += P[m][kk] * V[kk][d]; P through LDS for C->A layout transform
#pragma unroll
    for (int kk = 0; kk < 2; ++kk) {
      f16x8 pf0 = *(const f16x8*)&Ps[wave][0 + l15][kk * 32 + quad * 8];
      f16x8 pf1 = *(const f16x8*)&Ps[wave][16 + l15][kk * 32 + quad * 8];
#pragma unroll
      for (int dt = 0; dt < 8; ++dt) {
        f16x8 vf = *(const f16x8*)&Vs[dt * 16 + l15][kk * 32 + quad * 8];
        oacc[0][dt] = __builtin_amdgcn_mfma_f32_16x16x32_f16(pf0, vf, oacc[0][dt], 0, 0, 0);
        oacc[1][dt] = __builtin_amdgcn_mfma_f32_16x16x32_f16(pf1, vf, oacc[1][dt], 0, 0, 0);
      }
    }
    __syncthreads();
  }

  // write partials
#pragma unroll
  for (int mt = 0; mt < 2; ++mt) {
#pragma unroll
    for (int dt = 0; dt < 8; ++dt)
#pragma unroll
      for (int rr = 0; rr < 4; ++rr) {
        int row = mbase + mt * 16 + quad * 4 + rr;
        Op[((size_t)split * SEQ + row) * DH + dt * 16 + l15] = oacc[mt][dt][rr];
      }
    if (l15 == 0) {
#pragma unroll
      for (int rr = 0; rr < 4; ++rr) {
        int row = mbase + mt * 16 + quad * 4 + rr;
        ml[((size_t)split * SEQ + row) * 2 + 0] = mrow[mt][rr];
        ml[((size_t)split * SEQ + row) * 2 + 1] = lrow[mt][rr];
      }
    }
  }
}

// ---------------- combine KV splits ----------------
__global__ __launch_bounds__(256) void combine_kernel(const float* __restrict__ Op,
                                                      const float* __restrict__ ml,
                                                      float* __restrict__ out) {
  int idx = blockIdx.x * 256 + threadIdx.x;  // 0..SEQ*DH
  int row = idx >> 7;
  float ms[NSPLIT], ls[NSPLIT];
  float M = -1e30f;
#pragma unroll
  for (int s = 0; s < NSPLIT; ++s) {
    ms[s] = ml[((size_t)s * SEQ + row) * 2 + 0];
    ls[s] = ml[((size_t)s * SEQ + row) * 2 + 1];
    M = fmaxf(M, ms[s]);
  }
  float L = 0.f, o = 0.f;
#pragma unroll
  for (int s = 0; s < NSPLIT; ++s) {
    float w = __expf(ms[s] - M);
    L += ls[s] * w;
    o += w * Op[(size_t)s * SEQ * DH + idx];
  }
  out[idx] = o / L;
}

extern "C" void kernel_launch(void* const* d_in, const int* in_sizes, int n_in,
                              void* d_out, int out_size, void* d_ws, size_t ws_size,
                              hipStream_t stream) {
  const float* x = (const float*)d_in[0];   // [4096,4096]
  const float* W = (const float*)d_in[1];   // [384,4096]
  const float* b = (const float*)d_in[2];   // [384]
  float* out = (float*)d_out;               // [4096,128]
  char* ws = (char*)d_ws;

  f16*   Wh  = (f16*)(ws);                          // 3 MB
  f16*   qkv = (f16*)(ws + (3u << 20));             // 3 MB
  f16*   Vt  = (f16*)(ws + (6u << 20));             // 1 MB
  float* Op  = (float*)(ws + (7u << 20));           // 16 MB
  float* ml  = (float*)(ws + (23u << 20));          // 256 KB

  cvt_w_kernel<<<(384 * 4096 / 4) / 256, 256, 0, stream>>>((const float4*)W, (f16x4*)Wh);
  gemm_qkv<<<dim3(SEQ / 128, 3), 256, 0, stream>>>(x, Wh, b, qkv, Vt);
  attn_partial<<<dim3(SEQ / 128, NSPLIT), 256, 0, stream>>>(qkv, Vt, Op, ml);
  combine_kernel<<<(SEQ * DH) / 256, 256, 0, stream>>>(Op, ml, out);
}

// Round 2
// 165.686 us; speedup vs baseline: 1.5472x; 1.5472x over previous
//
#include <hip/hip_runtime.h>
#include <cstdint>
#include <cstddef>

typedef _Float16 f16;
typedef f16 f16x8 __attribute__((ext_vector_type(8)));
typedef f16 f16x4 __attribute__((ext_vector_type(4)));
typedef float f32x4 __attribute__((ext_vector_type(4)));

#define SEQ 4096
#define DH 128
#define QKV_LD 384   // 3*DH
#define LOG2E 1.44269504f

__device__ __forceinline__ float fast_exp2(float x) {
#if __has_builtin(__builtin_amdgcn_exp2f)
  return __builtin_amdgcn_exp2f(x);
#else
  return exp2f(x);
#endif
}

// ---------------- W fp32 -> fp16 ----------------
__global__ __launch_bounds__(256) void cvt_w_kernel(const float4* __restrict__ W,
                                                    f16x4* __restrict__ Wh) {
  int i = blockIdx.x * 256 + threadIdx.x;
  float4 v = W[i];
  f16x4 h; h[0] = (f16)v.x; h[1] = (f16)v.y; h[2] = (f16)v.z; h[3] = (f16)v.w;
  Wh[i] = h;
}

// ---------------- QKV GEMM with split-K: partial[split][i][j] = sum_{k in chunk} x[i][k]*W[j][k] ----
// BM=128, BN=128, BK=64; 4 waves 2x2, wave = 64x64 (4x4 MFMA frags). Grid (32, 3, SPLITS).
template <int SPLITS>
__global__ __launch_bounds__(256) void gemm_qkv(const float* __restrict__ x,
                                                const f16* __restrict__ Wh,
                                                f16* __restrict__ part) {
  __shared__ f16 Ax[128][72];  // +8 pad: row stride 144B
  __shared__ f16 Bx[128][72];
  const int m0 = blockIdx.x * 128;
  const int n0 = blockIdx.y * 128;
  const int split = blockIdx.z;
  const int k0 = split * (SEQ / SPLITS);
  const int tid = threadIdx.x;
  const int lane = tid & 63, wave = tid >> 6;
  const int wr = (wave >> 1) * 64, wc = (wave & 1) * 64;
  const int l15 = lane & 15, quad = lane >> 4;

  f32x4 acc[4][4] = {};

  for (int kt = k0; kt < k0 + SEQ / SPLITS; kt += 64) {
    // stage A: x[m0..+128][kt..+64] fp32 -> f16
#pragma unroll
    for (int r = 0; r < 8; ++r) {
      int c = tid + r * 256;
      int row = c >> 4, col = (c & 15) * 4;
      float4 v = *(const float4*)&x[(size_t)(m0 + row) * SEQ + kt + col];
      f16x4 h; h[0] = (f16)v.x; h[1] = (f16)v.y; h[2] = (f16)v.z; h[3] = (f16)v.w;
      *(f16x4*)&Ax[row][col] = h;
    }
    // stage B: Wh[n0..+128][kt..+64]
#pragma unroll
    for (int r = 0; r < 4; ++r) {
      int c = tid + r * 256;
      int row = c >> 3, col = (c & 7) * 8;
      *(f16x8*)&Bx[row][col] = *(const f16x8*)&Wh[(size_t)(n0 + row) * SEQ + kt + col];
    }
    __syncthreads();
#pragma unroll
    for (int ks = 0; ks < 2; ++ks) {
      f16x8 a[4], bb[4];
#pragma unroll
      for (int t = 0; t < 4; ++t) {
        a[t]  = *(const f16x8*)&Ax[wr + t * 16 + l15][ks * 32 + quad * 8];
        bb[t] = *(const f16x8*)&Bx[wc + t * 16 + l15][ks * 32 + quad * 8];
      }
#pragma unroll
      for (int mt = 0; mt < 4; ++mt)
#pragma unroll
        for (int nt = 0; nt < 4; ++nt)
          acc[mt][nt] = __builtin_amdgcn_mfma_f32_16x16x32_f16(a[mt], bb[nt], acc[mt][nt], 0, 0, 0);
    }
    __syncthreads();
  }

  // epilogue: f16 partial (no bias here)
  f16* pw = part + (size_t)split * SEQ * QKV_LD;
#pragma unroll
  for (int mt = 0; mt < 4; ++mt) {
#pragma unroll
    for (int nt = 0; nt < 4; ++nt) {
      int col = n0 + wc + nt * 16 + l15;
      int rowbase = m0 + wr + mt * 16 + quad * 4;
#pragma unroll
      for (int rr = 0; rr < 4; ++rr)
        pw[(size_t)(rowbase + rr) * QKV_LD + col] = (f16)acc[mt][nt][rr];
    }
  }
}

// ---------------- reduce split-K partials + bias -> qkv f16 ----------------
template <int SPLITS>
__global__ __launch_bounds__(256) void reduce_qkv(const f16* __restrict__ part,
                                                  const float* __restrict__ bias,
                                                  f16* __restrict__ qkv) {
  int i = (blockIdx.x * 256 + threadIdx.x) * 8;  // over SEQ*QKV_LD
  float acc[8] = {};
#pragma unroll
  for (int s = 0; s < SPLITS; ++s) {
    f16x8 p = *(const f16x8*)&part[(size_t)s * SEQ * QKV_LD + i];
#pragma unroll
    for (int j = 0; j < 8; ++j) acc[j] += (float)p[j];
  }
  int col = i % QKV_LD;
  f16x8 o;
#pragma unroll
  for (int j = 0; j < 8; ++j) o[j] = (f16)(acc[j] + bias[col + j]);
  *(f16x8*)&qkv[i] = o;
}

// ---------------- transpose V (qkv cols 256..384) -> Vt[128][4096] ----------------
__global__ __launch_bounds__(256) void transpose_v(const f16* __restrict__ qkv,
                                                   f16* __restrict__ Vt) {
  __shared__ f16 T[64][72];
  const int r0 = blockIdx.x * 64;   // V row (seq)
  const int c0 = blockIdx.y * 64;   // V col (d)
  const int tid = threadIdx.x;
#pragma unroll
  for (int rep = 0; rep < 2; ++rep) {
    int idx = rep * 256 + tid;
    int row = idx >> 3, col = (idx & 7) * 8;
    *(f16x8*)&T[row][col] = *(const f16x8*)&qkv[(size_t)(r0 + row) * QKV_LD + 256 + c0 + col];
  }
  __syncthreads();
#pragma unroll
  for (int rep = 0; rep < 2; ++rep) {
    int idx = rep * 256 + tid;
    int cc = idx >> 3, rb = (idx & 7) * 8;
    f16x8 o;
#pragma unroll
    for (int j = 0; j < 8; ++j) o[j] = T[rb + j][cc];
    *(f16x8*)&Vt[(size_t)(c0 + cc) * SEQ + r0 + rb] = o;
  }
}

// ---------------- Flash attention partial over a KV split ----------------
#define NSPLIT 16
#define KVRANGE (SEQ / NSPLIT)   // 256

__global__ __launch_bounds__(256, 2) void attn_partial(const f16* __restrict__ qkv,
                                                       const f16* __restrict__ Vt,
                                                       f16* __restrict__ Op,
                                                       float* __restrict__ ml) {
  __shared__ f16 Ks[64][136];
  __shared__ f16 Vs[128][72];
  __shared__ f16 Ps[4][32][72];

  const int q0 = blockIdx.x * 128;
  const int split = blockIdx.y;
  const int kv0 = split * KVRANGE;
  const int tid = threadIdx.x;
  const int lane = tid & 63, wave = tid >> 6;
  const int l15 = lane & 15, quad = lane >> 4;
  const int mbase = q0 + wave * 32;

  // Q fragments, pre-scaled by log2(e) so softmax runs in exp2 domain
  f16x8 qf[2][4];
#pragma unroll
  for (int mt = 0; mt < 2; ++mt)
#pragma unroll
    for (int ks = 0; ks < 4; ++ks) {
      f16x8 q = *(const f16x8*)&qkv[(size_t)(mbase + mt * 16 + l15) * QKV_LD + ks * 32 + quad * 8];
      qf[mt][ks] = q * (f16)LOG2E;
    }

  f32x4 oacc[2][8] = {};
  float mrow[2][4], lrow[2][4];
#pragma unroll
  for (int mt = 0; mt < 2; ++mt)
#pragma unroll
    for (int rr = 0; rr < 4; ++rr) { mrow[mt][rr] = -1e30f; lrow[mt][rr] = 0.f; }

  for (int it = 0; it < KVRANGE / 64; ++it) {
    const int k0 = kv0 + it * 64;
#pragma unroll
    for (int r = 0; r < 4; ++r) {
      int c = tid + r * 256;
      int row = c >> 4, col = (c & 15) * 8;
      *(f16x8*)&Ks[row][col] = *(const f16x8*)&qkv[(size_t)(k0 + row) * QKV_LD + DH + col];
    }
#pragma unroll
    for (int r = 0; r < 4; ++r) {
      int c = tid + r * 256;
      int row = c >> 3, col = (c & 7) * 8;
      *(f16x8*)&Vs[row][col] = *(const f16x8*)&Vt[(size_t)row * SEQ + k0 + col];
    }
    __syncthreads();

    // S (in log2 domain) = (Q*log2e) K^T
    f32x4 s[2][4] = {};
#pragma unroll
    for (int ks = 0; ks < 4; ++ks) {
      f16x8 kf[4];
#pragma unroll
      for (int nt = 0; nt < 4; ++nt)
        kf[nt] = *(const f16x8*)&Ks[nt * 16 + l15][ks * 32 + quad * 8];
#pragma unroll
      for (int mt = 0; mt < 2; ++mt)
#pragma unroll
        for (int nt = 0; nt < 4; ++nt)
          s[mt][nt] = __builtin_amdgcn_mfma_f32_16x16x32_f16(qf[mt][ks], kf[nt], s[mt][nt], 0, 0, 0);
    }

    // online softmax
#pragma unroll
    for (int mt = 0; mt < 2; ++mt) {
      float mnew[4], al[4];
#pragma unroll
      for (int rr = 0; rr < 4; ++rr) {
        float v = s[mt][0][rr];
#pragma unroll
        for (int nt = 1; nt < 4; ++nt) v = fmaxf(v, s[mt][nt][rr]);
        for (int off = 1; off < 16; off <<= 1) v = fmaxf(v, __shfl_xor(v, off));
        mnew[rr] = fmaxf(mrow[mt][rr], v);
        al[rr] = fast_exp2(mrow[mt][rr] - mnew[rr]);
        mrow[mt][rr] = mnew[rr];
      }
      float ls[4] = {0.f, 0.f, 0.f, 0.f};
#pragma unroll
      for (int nt = 0; nt < 4; ++nt)
#pragma unroll
        for (int rr = 0; rr < 4; ++rr) {
          float p = fast_exp2(s[mt][nt][rr] - mnew[rr]);
          ls[rr] += p;
          Ps[wave][mt * 16 + quad * 4 + rr][nt * 16 + l15] = (f16)p;
        }
#pragma unroll
      for (int rr = 0; rr < 4; ++rr) {
        float t = ls[rr];
        for (int off = 1; off < 16; off <<= 1) t += __shfl_xor(t, off);
        lrow[mt][rr] = lrow[mt][rr] * al[rr] + t;
      }
#pragma unroll
      for (int dt = 0; dt < 8; ++dt)
#pragma unroll
        for (int rr = 0; rr < 4; ++rr)
          oacc[mt][dt][rr] *= al[rr];
    }

    // PV
#pragma unroll
    for (int kk = 0; kk < 2; ++kk) {
      f16x8 pf0 = *(const f16x8*)&Ps[wave][0 + l15][kk * 32 + quad * 8];
      f16x8 pf1 = *(const f16x8*)&Ps[wave][16 + l15][kk * 32 + quad * 8];
#pragma unroll
      for (int dt = 0; dt < 8; ++dt) {
        f16x8 vf = *(const f16x8*)&Vs[dt * 16 + l15][kk * 32 + quad * 8];
        oacc[0][dt] = __builtin_amdgcn_mfma_f32_16x16x32_f16(pf0, vf, oacc[0][dt], 0, 0, 0);
        oacc[1][dt] = __builtin_amdgcn_mfma_f32_16x16x32_f16(pf1, vf, oacc[1][dt], 0, 0, 0);
      }
    }
    __syncthreads();
  }

  // write partials (O as f16; m,l as f32)
#pragma unroll
  for (int mt = 0; mt < 2; ++mt) {
#pragma unroll
    for (int dt = 0; dt < 8; ++dt)
#pragma unroll
      for (int rr = 0; rr < 4; ++rr) {
        int row = mbase + mt * 16 + quad * 4 + rr;
        Op[((size_t)split * SEQ + row) * DH + dt * 16 + l15] = (f16)oacc[mt][dt][rr];
      }
    if (l15 == 0) {
#pragma unroll
      for (int rr = 0; rr < 4; ++rr) {
        int row = mbase + mt * 16 + quad * 4 + rr;
        ml[((size_t)split * SEQ + row) * 2 + 0] = mrow[mt][rr];
        ml[((size_t)split * SEQ + row) * 2 + 1] = lrow[mt][rr];
      }
    }
  }
}

// ---------------- combine KV splits ----------------
__global__ __launch_bounds__(256) void combine_kernel(const f16* __restrict__ Op,
                                                      const float* __restrict__ ml,
                                                      float* __restrict__ out) {
  int idx = blockIdx.x * 256 + threadIdx.x;
  int row = idx >> 7;
  float ms[NSPLIT], ls[NSPLIT];
  float M = -1e30f;
#pragma unroll
  for (int s = 0; s < NSPLIT; ++s) {
    ms[s] = ml[((size_t)s * SEQ + row) * 2 + 0];
    ls[s] = ml[((size_t)s * SEQ + row) * 2 + 1];
    M = fmaxf(M, ms[s]);
  }
  float L = 0.f, o = 0.f;
#pragma unroll
  for (int s = 0; s < NSPLIT; ++s) {
    float w = fast_exp2(ms[s] - M);   // m's are in log2 domain
    L += ls[s] * w;
    o += w * (float)Op[(size_t)s * SEQ * DH + idx];
  }
  out[idx] = o / L;
}

extern "C" void kernel_launch(void* const* d_in, const int* in_sizes, int n_in,
                              void* d_out, int out_size, void* d_ws, size_t ws_size,
                              hipStream_t stream) {
  const float* x = (const float*)d_in[0];
  const float* W = (const float*)d_in[1];
  const float* b = (const float*)d_in[2];
  float* out = (float*)d_out;
  char* ws = (char*)d_ws;

  f16*   Wh   = (f16*)(ws);                      // [0, 3M)
  f16*   qkv  = (f16*)(ws + (3u << 20));         // [3M, 6M)
  f16*   Vt   = (f16*)(ws + (6u << 20));         // [6M, 7M)
  float* ml   = (float*)(ws + (7u << 20));       // [7M, 7.5M)  16*4096*2*4 = 512K
  char*  scr  = ws + (7u << 20) + (1u << 19);    // [7.5M, ...) gemm partials, then Op
  f16*   part = (f16*)scr;                       // SPLITS * 3MB
  f16*   Op   = (f16*)scr;                       // 16 MB (reuses partials region)

  cvt_w_kernel<<<(384 * 4096 / 4) / 256, 256, 0, stream>>>((const float4*)W, (f16x4*)Wh);

  bool big = ws_size >= ((size_t)32u << 20);
  if (big) {
    gemm_qkv<8><<<dim3(SEQ / 128, 3, 8), 256, 0, stream>>>(x, Wh, part);
    reduce_qkv<8><<<SEQ * QKV_LD / 8 / 256, 256, 0, stream>>>(part, b, qkv);
  } else {
    gemm_qkv<4><<<dim3(SEQ / 128, 3, 4), 256, 0, stream>>>(x, Wh, part);
    reduce_qkv<4><<<SEQ * QKV_LD / 8 / 256, 256, 0, stream>>>(part, b, qkv);
  }
  transpose_v<<<dim3(SEQ / 64, DH / 64), 256, 0, stream>>>(qkv, Vt);
  attn_partial<<<dim3(SEQ / 128, NSPLIT), 256, 0, stream>>>(qkv, Vt, Op, ml);
  combine_kernel<<<(SEQ * DH) / 256, 256, 0, stream>>>(Op, ml, out);
}

// Round 3
// 154.547 us; speedup vs baseline: 1.6587x; 1.0721x over previous
//
#include <hip/hip_runtime.h>
#include <cstdint>
#include <cstddef>

typedef _Float16 f16;
typedef f16 f16x8 __attribute__((ext_vector_type(8)));
typedef f16 f16x4 __attribute__((ext_vector_type(4)));
typedef float f32x4 __attribute__((ext_vector_type(4)));

#define SEQ 4096
#define DH 128
#define QKV_LD 384   // 3*DH
#define LOG2E 1.44269504f

__device__ __forceinline__ float fast_exp2(float x) {
#if __has_builtin(__builtin_amdgcn_exp2f)
  return __builtin_amdgcn_exp2f(x);
#else
  return exp2f(x);
#endif
}

// ---- DPP 16-lane reductions (VALU pipe, not LDS) ----
// ctrl: 0x128=row_ror:8, 0x124=row_ror:4, 0x4E=quad_perm xor2, 0xB1=quad_perm xor1
template <int CTRL>
__device__ __forceinline__ float dppf(float x) {
  int r = __builtin_amdgcn_mov_dpp(__builtin_bit_cast(int, x), CTRL, 0xF, 0xF, true);
  return __builtin_bit_cast(float, r);
}
__device__ __forceinline__ float rmax16(float v) {
  v = fmaxf(v, dppf<0x128>(v));
  v = fmaxf(v, dppf<0x124>(v));
  v = fmaxf(v, dppf<0x4E>(v));
  v = fmaxf(v, dppf<0xB1>(v));
  return v;
}
__device__ __forceinline__ float rsum16(float v) {
  v += dppf<0x128>(v);
  v += dppf<0x124>(v);
  v += dppf<0x4E>(v);
  v += dppf<0xB1>(v);
  return v;
}

// ---------------- W fp32 -> fp16 ----------------
__global__ __launch_bounds__(256) void cvt_w_kernel(const float4* __restrict__ W,
                                                    f16x4* __restrict__ Wh) {
  int i = blockIdx.x * 256 + threadIdx.x;
  float4 v = W[i];
  f16x4 h; h[0] = (f16)v.x; h[1] = (f16)v.y; h[2] = (f16)v.z; h[3] = (f16)v.w;
  Wh[i] = h;
}

// ---------------- QKV GEMM, split-K, full-N per block ----------------
// BM=64, BN=384 (all of it), BK=64. Grid (SEQ/64, SPLITS) = (64, 8) = 512 blocks.
// x is read from HBM exactly once; A-tile converted fp32->f16 exactly once.
// 4 waves each own a 64x96 tile (4x6 MFMA frags).
template <int SPLITS>
__global__ __launch_bounds__(256, 2) void gemm_qkv(const float* __restrict__ x,
                                                   const f16* __restrict__ Wh,
                                                   f16* __restrict__ part) {
  __shared__ f16 Ax[64][72];    // 9.2 KB  (+8 pad -> 144B stride, 2-way banks only)
  __shared__ f16 Bx[384][72];   // 55.3 KB
  const int m0 = blockIdx.x * 64;
  const int split = blockIdx.y;
  const int k0 = split * (SEQ / SPLITS);
  const int tid = threadIdx.x;
  const int lane = tid & 63, wave = tid >> 6;
  const int nb = wave * 96;
  const int l15 = lane & 15, quad = lane >> 4;

  f32x4 acc[4][6] = {};

  for (int kt = k0; kt < k0 + SEQ / SPLITS; kt += 64) {
    // stage A: x[m0..+64][kt..+64] fp32 -> f16 (1024 float4 / 256 thr)
#pragma unroll
    for (int r = 0; r < 4; ++r) {
      int c = tid + r * 256;
      int row = c >> 4, col = (c & 15) * 4;
      float4 v = *(const float4*)&x[(size_t)(m0 + row) * SEQ + kt + col];
      f16x4 h; h[0] = (f16)v.x; h[1] = (f16)v.y; h[2] = (f16)v.z; h[3] = (f16)v.w;
      *(f16x4*)&Ax[row][col] = h;
    }
    // stage B: Wh[0..384][kt..+64] (3072 f16x8 / 256 thr)
#pragma unroll
    for (int r = 0; r < 12; ++r) {
      int c = tid + r * 256;
      int row = c >> 3, col = (c & 7) * 8;
      *(f16x8*)&Bx[row][col] = *(const f16x8*)&Wh[(size_t)row * SEQ + kt + col];
    }
    __syncthreads();
#pragma unroll
    for (int ks = 0; ks < 2; ++ks) {
      f16x8 a[4], bb[6];
#pragma unroll
      for (int t = 0; t < 4; ++t)
        a[t] = *(const f16x8*)&Ax[t * 16 + l15][ks * 32 + quad * 8];
#pragma unroll
      for (int t = 0; t < 6; ++t)
        bb[t] = *(const f16x8*)&Bx[nb + t * 16 + l15][ks * 32 + quad * 8];
#pragma unroll
      for (int mt = 0; mt < 4; ++mt)
#pragma unroll
        for (int nt = 0; nt < 6; ++nt)
          acc[mt][nt] = __builtin_amdgcn_mfma_f32_16x16x32_f16(a[mt], bb[nt], acc[mt][nt], 0, 0, 0);
    }
    __syncthreads();
  }

  // epilogue: f16 partials
  f16* pw = part + (size_t)split * SEQ * QKV_LD;
#pragma unroll
  for (int mt = 0; mt < 4; ++mt) {
#pragma unroll
    for (int nt = 0; nt < 6; ++nt) {
      int col = nb + nt * 16 + l15;
      int rowbase = m0 + mt * 16 + quad * 4;
#pragma unroll
      for (int rr = 0; rr < 4; ++rr)
        pw[(size_t)(rowbase + rr) * QKV_LD + col] = (f16)acc[mt][nt][rr];
    }
  }
}

// ---------------- reduce split-K partials + bias -> qkv f16 ----------------
template <int SPLITS>
__global__ __launch_bounds__(256) void reduce_qkv(const f16* __restrict__ part,
                                                  const float* __restrict__ bias,
                                                  f16* __restrict__ qkv) {
  int i = (blockIdx.x * 256 + threadIdx.x) * 8;
  float acc[8] = {};
#pragma unroll
  for (int s = 0; s < SPLITS; ++s) {
    f16x8 p = *(const f16x8*)&part[(size_t)s * SEQ * QKV_LD + i];
#pragma unroll
    for (int j = 0; j < 8; ++j) acc[j] += (float)p[j];
  }
  int col = i % QKV_LD;
  f16x8 o;
#pragma unroll
  for (int j = 0; j < 8; ++j) o[j] = (f16)(acc[j] + bias[col + j]);
  *(f16x8*)&qkv[i] = o;
}

// ---------------- transpose V (qkv cols 256..384) -> Vt[128][4096] ----------------
__global__ __launch_bounds__(256) void transpose_v(const f16* __restrict__ qkv,
                                                   f16* __restrict__ Vt) {
  __shared__ f16 T[64][72];
  const int r0 = blockIdx.x * 64;
  const int c0 = blockIdx.y * 64;
  const int tid = threadIdx.x;
#pragma unroll
  for (int rep = 0; rep < 2; ++rep) {
    int idx = rep * 256 + tid;
    int row = idx >> 3, col = (idx & 7) * 8;
    *(f16x8*)&T[row][col] = *(const f16x8*)&qkv[(size_t)(r0 + row) * QKV_LD + 256 + c0 + col];
  }
  __syncthreads();
#pragma unroll
  for (int rep = 0; rep < 2; ++rep) {
    int idx = rep * 256 + tid;
    int cc = idx >> 3, rb = (idx & 7) * 8;
    f16x8 o;
#pragma unroll
    for (int j = 0; j < 8; ++j) o[j] = T[rb + j][cc];
    *(f16x8*)&Vt[(size_t)(c0 + cc) * SEQ + r0 + rb] = o;
  }
}

// ---------------- Flash attention partial over a KV split ----------------
#define NSPLIT 16
#define KVRANGE (SEQ / NSPLIT)   // 256

__global__ __launch_bounds__(256, 2) void attn_partial(const f16* __restrict__ qkv,
                                                       const f16* __restrict__ Vt,
                                                       f16* __restrict__ Op,
                                                       float* __restrict__ ml) {
  __shared__ f16 Ks[64][136];       // 17.4 KB
  __shared__ f16 Vs[128][72];       // 18.4 KB
  __shared__ f16 Pt[4][64][36];     // 18.4 KB, P transposed: [k][m]

  const int q0 = blockIdx.x * 128;
  const int split = blockIdx.y;
  const int kv0 = split * KVRANGE;
  const int tid = threadIdx.x;
  const int lane = tid & 63, wave = tid >> 6;
  const int l15 = lane & 15, quad = lane >> 4;
  const int mbase = q0 + wave * 32;

  // Q fragments, pre-scaled by log2(e): softmax in exp2 domain
  f16x8 qf[2][4];
#pragma unroll
  for (int mt = 0; mt < 2; ++mt)
#pragma unroll
    for (int ks = 0; ks < 4; ++ks) {
      f16x8 q = *(const f16x8*)&qkv[(size_t)(mbase + mt * 16 + l15) * QKV_LD + ks * 32 + quad * 8];
      qf[mt][ks] = q * (f16)LOG2E;
    }

  f32x4 oacc[2][8] = {};
  float mrow[2][4], lrow[2][4];
#pragma unroll
  for (int mt = 0; mt < 2; ++mt)
#pragma unroll
    for (int rr = 0; rr < 4; ++rr) { mrow[mt][rr] = -1e30f; lrow[mt][rr] = 0.f; }

  for (int it = 0; it < KVRANGE / 64; ++it) {
    const int k0 = kv0 + it * 64;
#pragma unroll
    for (int r = 0; r < 4; ++r) {
      int c = tid + r * 256;
      int row = c >> 4, col = (c & 15) * 8;
      *(f16x8*)&Ks[row][col] = *(const f16x8*)&qkv[(size_t)(k0 + row) * QKV_LD + DH + col];
    }
#pragma unroll
    for (int r = 0; r < 4; ++r) {
      int c = tid + r * 256;
      int row = c >> 3, col = (c & 7) * 8;
      *(f16x8*)&Vs[row][col] = *(const f16x8*)&Vt[(size_t)row * SEQ + k0 + col];
    }
    __syncthreads();

    // S (log2 domain) = (Q*log2e) K^T  : 32 rows x 64 keys per wave
    f32x4 s[2][4] = {};
#pragma unroll
    for (int ks = 0; ks < 4; ++ks) {
      f16x8 kf[4];
#pragma unroll
      for (int nt = 0; nt < 4; ++nt)
        kf[nt] = *(const f16x8*)&Ks[nt * 16 + l15][ks * 32 + quad * 8];
#pragma unroll
      for (int mt = 0; mt < 2; ++mt)
#pragma unroll
        for (int nt = 0; nt < 4; ++nt)
          s[mt][nt] = __builtin_amdgcn_mfma_f32_16x16x32_f16(qf[mt][ks], kf[nt], s[mt][nt], 0, 0, 0);
    }

    // online softmax; DPP reductions; P written transposed+packed
#pragma unroll
    for (int mt = 0; mt < 2; ++mt) {
      float mnew[4], al[4];
#pragma unroll
      for (int rr = 0; rr < 4; ++rr) {
        float v = fmaxf(fmaxf(s[mt][0][rr], s[mt][1][rr]), fmaxf(s[mt][2][rr], s[mt][3][rr]));
        v = rmax16(v);
        mnew[rr] = fmaxf(mrow[mt][rr], v);
        al[rr] = fast_exp2(mrow[mt][rr] - mnew[rr]);
        mrow[mt][rr] = mnew[rr];
      }
      float ls[4] = {0.f, 0.f, 0.f, 0.f};
#pragma unroll
      for (int nt = 0; nt < 4; ++nt) {
        f16x4 pk;
#pragma unroll
        for (int rr = 0; rr < 4; ++rr) {
          float p = fast_exp2(s[mt][nt][rr] - mnew[rr]);
          ls[rr] += p;
          pk[rr] = (f16)p;
        }
        // Pt[k][m]: k = nt*16+l15, m = mt*16+quad*4 .. +3  -> one b64 store
        *(f16x4*)&Pt[wave][nt * 16 + l15][mt * 16 + quad * 4] = pk;
      }
#pragma unroll
      for (int rr = 0; rr < 4; ++rr)
        lrow[mt][rr] = lrow[mt][rr] * al[rr] + rsum16(ls[rr]);
#pragma unroll
      for (int dt = 0; dt < 8; ++dt)
#pragma unroll
        for (int rr = 0; rr < 4; ++rr)
          oacc[mt][dt][rr] *= al[rr];
    }
    __syncthreads();  // Pt visible within wave only? same wave writes+reads; but Ks/Vs restage below needs it anyway

    // PV: A-frag gather from Pt (transposed layout)
#pragma unroll
    for (int kk = 0; kk < 2; ++kk) {
      f16x8 pf[2];
#pragma unroll
      for (int mt = 0; mt < 2; ++mt)
#pragma unroll
        for (int j = 0; j < 8; ++j)
          pf[mt][j] = Pt[wave][kk * 32 + quad * 8 + j][mt * 16 + l15];
#pragma unroll
      for (int dt = 0; dt < 8; ++dt) {
        f16x8 vf = *(const f16x8*)&Vs[dt * 16 + l15][kk * 32 + quad * 8];
        oacc[0][dt] = __builtin_amdgcn_mfma_f32_16x16x32_f16(pf[0], vf, oacc[0][dt], 0, 0, 0);
        oacc[1][dt] = __builtin_amdgcn_mfma_f32_16x16x32_f16(pf[1], vf, oacc[1][dt], 0, 0, 0);
      }
    }
    __syncthreads();
  }

  // write partials (O f16; m,l f32)
#pragma unroll
  for (int mt = 0; mt < 2; ++mt) {
#pragma unroll
    for (int dt = 0; dt < 8; ++dt)
#pragma unroll
      for (int rr = 0; rr < 4; ++rr) {
        int row = mbase + mt * 16 + quad * 4 + rr;
        Op[((size_t)split * SEQ + row) * DH + dt * 16 + l15] = (f16)oacc[mt][dt][rr];
      }
    if (l15 == 0) {
#pragma unroll
      for (int rr = 0; rr < 4; ++rr) {
        int row = mbase + mt * 16 + quad * 4 + rr;
        ml[((size_t)split * SEQ + row) * 2 + 0] = mrow[mt][rr];
        ml[((size_t)split * SEQ + row) * 2 + 1] = lrow[mt][rr];
      }
    }
  }
}

// ---------------- combine KV splits ----------------
__global__ __launch_bounds__(256) void combine_kernel(const f16* __restrict__ Op,
                                                      const float* __restrict__ ml,
                                                      float* __restrict__ out) {
  int idx = blockIdx.x * 256 + threadIdx.x;
  int row = idx >> 7;
  float ms[NSPLIT], ls[NSPLIT];
  float M = -1e30f;
#pragma unroll
  for (int s = 0; s < NSPLIT; ++s) {
    ms[s] = ml[((size_t)s * SEQ + row) * 2 + 0];
    ls[s] = ml[((size_t)s * SEQ + row) * 2 + 1];
    M = fmaxf(M, ms[s]);
  }
  float L = 0.f, o = 0.f;
#pragma unroll
  for (int s = 0; s < NSPLIT; ++s) {
    float w = fast_exp2(ms[s] - M);
    L += ls[s] * w;
    o += w * (float)Op[(size_t)s * SEQ * DH + idx];
  }
  out[idx] = o / L;
}

extern "C" void kernel_launch(void* const* d_in, const int* in_sizes, int n_in,
                              void* d_out, int out_size, void* d_ws, size_t ws_size,
                              hipStream_t stream) {
  const float* x = (const float*)d_in[0];
  const float* W = (const float*)d_in[1];
  const float* b = (const float*)d_in[2];
  float* out = (float*)d_out;
  char* ws = (char*)d_ws;

  f16*   Wh   = (f16*)(ws);                      // [0, 3M)
  f16*   qkv  = (f16*)(ws + (3u << 20));         // [3M, 6M)
  f16*   Vt   = (f16*)(ws + (6u << 20));         // [6M, 7M)
  float* ml   = (float*)(ws + (7u << 20));       // [7M, 7.5M)
  char*  scr  = ws + (7u << 20) + (1u << 19);    // gemm partials, later Op
  f16*   part = (f16*)scr;                       // SPLITS * 3MB
  f16*   Op   = (f16*)scr;                       // 16 MB (reuses partials region)

  cvt_w_kernel<<<(384 * 4096 / 4) / 256, 256, 0, stream>>>((const float4*)W, (f16x4*)Wh);

  bool big = ws_size >= ((size_t)31u << 20) + ((size_t)1u << 19);
  if (big) {
    gemm_qkv<8><<<dim3(SEQ / 64, 8), 256, 0, stream>>>(x, Wh, part);
    reduce_qkv<8><<<SEQ * QKV_LD / 8 / 256, 256, 0, stream>>>(part, b, qkv);
  } else {
    gemm_qkv<4><<<dim3(SEQ / 64, 4), 256, 0, stream>>>(x, Wh, part);
    reduce_qkv<4><<<SEQ * QKV_LD / 8 / 256, 256, 0, stream>>>(part, b, qkv);
  }
  transpose_v<<<dim3(SEQ / 64, DH / 64), 256, 0, stream>>>(qkv, Vt);
  attn_partial<<<dim3(SEQ / 128, NSPLIT), 256, 0, stream>>>(qkv, Vt, Op, ml);
  combine_kernel<<<(SEQ * DH) / 256, 256, 0, stream>>>(Op, ml, out);
}

// Round 4
// 151.968 us; speedup vs baseline: 1.6869x; 1.0170x over previous
//
#include <hip/hip_runtime.h>
#include <cstdint>
#include <cstddef>

typedef _Float16 f16;
typedef f16 f16x8 __attribute__((ext_vector_type(8)));
typedef f16 f16x4 __attribute__((ext_vector_type(4)));
typedef float f32x4 __attribute__((ext_vector_type(4)));

#define SEQ 4096
#define DH 128
#define QKV_LD 384   // 3*DH
#define LOG2E 1.44269504f

__device__ __forceinline__ float fast_exp2(float x) {
#if __has_builtin(__builtin_amdgcn_exp2f)
  return __builtin_amdgcn_exp2f(x);
#else
  return exp2f(x);
#endif
}

// async global->LDS DMA, 16B per lane. LDS dest MUST be wave-uniform base + lane*16.
__device__ __forceinline__ void gl_lds16(const void* g, void* l) {
  __builtin_amdgcn_global_load_lds((const __attribute__((address_space(1))) void*)g,
                                   (__attribute__((address_space(3))) void*)l, 16, 0, 0);
}

// ---------------- W fp32 -> fp16 ----------------
__global__ __launch_bounds__(256) void cvt_w_kernel(const float4* __restrict__ W,
                                                    f16x4* __restrict__ Wh) {
  int i = blockIdx.x * 256 + threadIdx.x;
  float4 v = W[i];
  f16x4 h; h[0] = (f16)v.x; h[1] = (f16)v.y; h[2] = (f16)v.z; h[3] = (f16)v.w;
  Wh[i] = h;
}

// ---------------- QKV GEMM, split-K, full-N per block ----------------
// BM=64, BN=384, BK=64. Grid (64, SPLITS). B staged by global_load_lds into an
// unpadded XOR-swizzled LDS image (chunk^=row&7): satisfies the lane*16 LDS-dest
// constraint AND gives conflict-free b128 frag reads. A staged manually (fp32->f16).
template <int SPLITS>
__global__ __launch_bounds__(256, 2) void gemm_qkv(const float* __restrict__ x,
                                                   const f16* __restrict__ Wh,
                                                   f16* __restrict__ part) {
  __shared__ __align__(16) f16 Ax[64][72];          // padded (+8): 144B row stride
  __shared__ __align__(16) f16 Bx[QKV_LD * 64];     // unpadded 384x64, swizzled chunks
  const int m0 = blockIdx.x * 64;
  const int split = blockIdx.y;
  const int kc = SEQ / SPLITS;
  const int k0 = split * kc;
  const int tid = threadIdx.x;
  const int lane = tid & 63;
  const int wave = tid >> 6;
  const int nb = wave * 96;
  const int l15 = lane & 15, quad = lane >> 4;

  f32x4 acc[4][6] = {};

  for (int kt = k0; kt < k0 + kc; kt += 64) {
    // B: 12 async DMA issues/thread. LDS linear index c*8 halves = base + lane*16B.
#pragma unroll
    for (int r = 0; r < 12; ++r) {
      int c = r * 256 + tid;              // 0..3071 over 384 rows x 8 chunks
      int row = c >> 3, ch = c & 7;
      const f16* src = &Wh[(size_t)row * SEQ + kt + ((ch ^ (row & 7)) << 3)];
      gl_lds16(src, &Bx[(size_t)c << 3]);
    }
    // A: x[m0..+64][kt..+64] fp32 -> f16 (manual: needs conversion)
#pragma unroll
    for (int r = 0; r < 4; ++r) {
      int c = r * 256 + tid;
      int row = c >> 4, col = (c & 15) * 4;
      float4 v = *(const float4*)&x[(size_t)(m0 + row) * SEQ + kt + col];
      f16x4 h; h[0] = (f16)v.x; h[1] = (f16)v.y; h[2] = (f16)v.z; h[3] = (f16)v.w;
      *(f16x4*)&Ax[row][col] = h;
    }
    __syncthreads();   // drains vmcnt (incl. DMA) + lgkm
#pragma unroll
    for (int ks = 0; ks < 2; ++ks) {
      f16x8 a[4], bb[6];
#pragma unroll
      for (int t = 0; t < 4; ++t)
        a[t] = *(const f16x8*)&Ax[t * 16 + l15][ks * 32 + quad * 8];
#pragma unroll
      for (int t = 0; t < 6; ++t) {
        int n = nb + t * 16 + l15;                 // n&7 == l15&7 (nb, t*16 are mult of 8)
        int ch = (ks * 4 + quad) ^ (l15 & 7);      // un-swizzle
        bb[t] = *(const f16x8*)&Bx[((size_t)n << 6) + (ch << 3)];
      }
#pragma unroll
      for (int mt = 0; mt < 4; ++mt)
#pragma unroll
        for (int nt = 0; nt < 6; ++nt)
          acc[mt][nt] = __builtin_amdgcn_mfma_f32_16x16x32_f16(a[mt], bb[nt], acc[mt][nt], 0, 0, 0);
    }
    __syncthreads();
  }

  // epilogue: f16 partials
  f16* pw = part + (size_t)split * SEQ * QKV_LD;
#pragma unroll
  for (int mt = 0; mt < 4; ++mt) {
#pragma unroll
    for (int nt = 0; nt < 6; ++nt) {
      int col = nb + nt * 16 + l15;
      int rowbase = m0 + mt * 16 + quad * 4;
#pragma unroll
      for (int rr = 0; rr < 4; ++rr)
        pw[(size_t)(rowbase + rr) * QKV_LD + col] = (f16)acc[mt][nt][rr];
    }
  }
}

// ---------------- reduce split-K partials + bias -> qkv f16 ----------------
template <int SPLITS>
__global__ __launch_bounds__(256) void reduce_qkv(const f16* __restrict__ part,
                                                  const float* __restrict__ bias,
                                                  f16* __restrict__ qkv) {
  int i = (blockIdx.x * 256 + threadIdx.x) * 8;
  float acc[8] = {};
#pragma unroll
  for (int s = 0; s < SPLITS; ++s) {
    f16x8 p = *(const f16x8*)&part[(size_t)s * SEQ * QKV_LD + i];
#pragma unroll
    for (int j = 0; j < 8; ++j) acc[j] += (float)p[j];
  }
  int col = i % QKV_LD;
  f16x8 o;
#pragma unroll
  for (int j = 0; j < 8; ++j) o[j] = (f16)(acc[j] + bias[col + j]);
  *(f16x8*)&qkv[i] = o;
}

// ---------------- transpose V (qkv cols 256..384) -> Vt[128][4096] ----------------
__global__ __launch_bounds__(256) void transpose_v(const f16* __restrict__ qkv,
                                                   f16* __restrict__ Vt) {
  __shared__ __align__(16) f16 T[64][72];
  const int r0 = blockIdx.x * 64;
  const int c0 = blockIdx.y * 64;
  const int tid = threadIdx.x;
#pragma unroll
  for (int rep = 0; rep < 2; ++rep) {
    int idx = rep * 256 + tid;
    int row = idx >> 3, col = (idx & 7) * 8;
    *(f16x8*)&T[row][col] = *(const f16x8*)&qkv[(size_t)(r0 + row) * QKV_LD + 256 + c0 + col];
  }
  __syncthreads();
#pragma unroll
  for (int rep = 0; rep < 2; ++rep) {
    int idx = rep * 256 + tid;
    int cc = idx >> 3, rb = (idx & 7) * 8;
    f16x8 o;
#pragma unroll
    for (int j = 0; j < 8; ++j) o[j] = T[rb + j][cc];
    *(f16x8*)&Vt[(size_t)(c0 + cc) * SEQ + r0 + rb] = o;
  }
}

// ---------------- Flash attention partial over a KV split ----------------
// S^T scheme: S^T = K·Q^T via operand swap => C-layout holds 4 consecutive k per
// lane => packed b64 P-stores into Ps[m][k], pure-b128 PV frag reads.
#define NSPLIT 16
#define KVRANGE (SEQ / NSPLIT)   // 256

__global__ __launch_bounds__(256, 2) void attn_partial(const f16* __restrict__ qkv,
                                                       const f16* __restrict__ Vt,
                                                       f16* __restrict__ Op,
                                                       float* __restrict__ ml) {
  __shared__ __align__(16) f16 Ks[64][136];     // 64 keys x 128 d (+8 pad)
  __shared__ __align__(16) f16 Vs[128][72];     // V^T: 128 d x 64 k (+8 pad)
  __shared__ __align__(16) f16 Ps[4][32][72];   // per-wave P[m][k] (+8 pad)

  const int q0 = blockIdx.x * 128;
  const int split = blockIdx.y;
  const int kv0 = split * KVRANGE;
  const int tid = threadIdx.x;
  const int lane = tid & 63, wave = tid >> 6;
  const int l15 = lane & 15, quad = lane >> 4;
  const int mbase = q0 + wave * 32;

  // Q fragments (pre-scaled by log2 e): used as the B-operand of S^T = K·Q^T.
  // Content identical to the A-layout load: lane holds Q[m=l15][c=quad*8+j].
  f16x8 qf[2][4];
#pragma unroll
  for (int mt = 0; mt < 2; ++mt)
#pragma unroll
    for (int ks = 0; ks < 4; ++ks) {
      f16x8 q = *(const f16x8*)&qkv[(size_t)(mbase + mt * 16 + l15) * QKV_LD + ks * 32 + quad * 8];
      qf[mt][ks] = q * (f16)LOG2E;
    }

  f32x4 oacc[2][8] = {};
  float mrow[2] = {-1e30f, -1e30f};
  float lrow[2] = {0.f, 0.f};

  for (int it = 0; it < KVRANGE / 64; ++it) {
    const int k0 = kv0 + it * 64;
#pragma unroll
    for (int r = 0; r < 4; ++r) {
      int c = tid + r * 256;
      int row = c >> 4, col = (c & 15) * 8;
      *(f16x8*)&Ks[row][col] = *(const f16x8*)&qkv[(size_t)(k0 + row) * QKV_LD + DH + col];
    }
#pragma unroll
    for (int r = 0; r < 4; ++r) {
      int c = tid + r * 256;
      int row = c >> 3, col = (c & 7) * 8;
      *(f16x8*)&Vs[row][col] = *(const f16x8*)&Vt[(size_t)row * SEQ + k0 + col];
    }
    __syncthreads();

    // S^T[k][m]: A=K-frag, B=Q-frag. Lane holds S[m=l15(+mt*16)][k=kt*16+quad*4+rr].
    f32x4 st[4][2] = {};   // [kt][mt]
#pragma unroll
    for (int ks = 0; ks < 4; ++ks) {
      f16x8 kf[4];
#pragma unroll
      for (int kt = 0; kt < 4; ++kt)
        kf[kt] = *(const f16x8*)&Ks[kt * 16 + l15][ks * 32 + quad * 8];
#pragma unroll
      for (int kt = 0; kt < 4; ++kt)
#pragma unroll
        for (int mt = 0; mt < 2; ++mt)
          st[kt][mt] = __builtin_amdgcn_mfma_f32_16x16x32_f16(kf[kt], qf[mt][ks], st[kt][mt], 0, 0, 0);
    }

    // online softmax: row m = l15 (+mt*16); reduce over rr,kt in-lane + 2 shfl over quads
    float al[2];
#pragma unroll
    for (int mt = 0; mt < 2; ++mt) {
      float v = -1e30f;
#pragma unroll
      for (int kt = 0; kt < 4; ++kt)
#pragma unroll
        for (int rr = 0; rr < 4; ++rr) v = fmaxf(v, st[kt][mt][rr]);
      v = fmaxf(v, __shfl_xor(v, 16));
      v = fmaxf(v, __shfl_xor(v, 32));
      float mnew = fmaxf(mrow[mt], v);
      al[mt] = fast_exp2(mrow[mt] - mnew);
      mrow[mt] = mnew;
      float ls = 0.f;
#pragma unroll
      for (int kt = 0; kt < 4; ++kt) {
        f16x4 pk;
#pragma unroll
        for (int rr = 0; rr < 4; ++rr) {
          float p = fast_exp2(st[kt][mt][rr] - mnew);
          ls += p;
          pk[rr] = (f16)p;
        }
        // Ps[m][k]: 4 consecutive k -> one b64 store
        *(f16x4*)&Ps[wave][mt * 16 + l15][kt * 16 + quad * 4] = pk;
      }
      ls += __shfl_xor(ls, 16);
      ls += __shfl_xor(ls, 32);
      lrow[mt] = lrow[mt] * al[mt] + ls;
    }

    // broadcast alpha (per m=l15) into O's C-layout rows (m=quad*4+rr)
    float alr[2][4];
#pragma unroll
    for (int mt = 0; mt < 2; ++mt)
#pragma unroll
      for (int rr = 0; rr < 4; ++rr)
        alr[mt][rr] = __shfl(al[mt], quad * 4 + rr);
#pragma unroll
    for (int mt = 0; mt < 2; ++mt)
#pragma unroll
      for (int dt = 0; dt < 8; ++dt)
#pragma unroll
        for (int rr = 0; rr < 4; ++rr)
          oacc[mt][dt][rr] *= alr[mt][rr];

    // PV: A=P-frag (b128 from Ps[m][k]), B=V^T-frag (b128 from Vs[d][k]); O standard layout
#pragma unroll
    for (int kk = 0; kk < 2; ++kk) {
      f16x8 pf[2];
#pragma unroll
      for (int mt = 0; mt < 2; ++mt)
        pf[mt] = *(const f16x8*)&Ps[wave][mt * 16 + l15][kk * 32 + quad * 8];
#pragma unroll
      for (int dt = 0; dt < 8; ++dt) {
        f16x8 vf = *(const f16x8*)&Vs[dt * 16 + l15][kk * 32 + quad * 8];
#pragma unroll
        for (int mt = 0; mt < 2; ++mt)
          oacc[mt][dt] = __builtin_amdgcn_mfma_f32_16x16x32_f16(pf[mt], vf, oacc[mt][dt], 0, 0, 0);
      }
    }
    __syncthreads();
  }

  // write partials: O rows m = mbase+mt*16+quad*4+rr, cols d = dt*16+l15 (coalesced-ish)
#pragma unroll
  for (int mt = 0; mt < 2; ++mt)
#pragma unroll
    for (int dt = 0; dt < 8; ++dt)
#pragma unroll
      for (int rr = 0; rr < 4; ++rr) {
        int row = mbase + mt * 16 + quad * 4 + rr;
        Op[((size_t)split * SEQ + row) * DH + dt * 16 + l15] = (f16)oacc[mt][dt][rr];
      }
  if (quad == 0) {
#pragma unroll
    for (int mt = 0; mt < 2; ++mt) {
      int row = mbase + mt * 16 + l15;
      ml[((size_t)split * SEQ + row) * 2 + 0] = mrow[mt];
      ml[((size_t)split * SEQ + row) * 2 + 1] = lrow[mt];
    }
  }
}

// ---------------- combine KV splits ----------------
__global__ __launch_bounds__(256) void combine_kernel(const f16* __restrict__ Op,
                                                      const float* __restrict__ ml,
                                                      float* __restrict__ out) {
  int idx = blockIdx.x * 256 + threadIdx.x;
  int row = idx >> 7;
  float ms[NSPLIT], ls[NSPLIT];
  float M = -1e30f;
#pragma unroll
  for (int s = 0; s < NSPLIT; ++s) {
    ms[s] = ml[((size_t)s * SEQ + row) * 2 + 0];
    ls[s] = ml[((size_t)s * SEQ + row) * 2 + 1];
    M = fmaxf(M, ms[s]);
  }
  float L = 0.f, o = 0.f;
#pragma unroll
  for (int s = 0; s < NSPLIT; ++s) {
    float w = fast_exp2(ms[s] - M);   // log2-domain m's
    L += ls[s] * w;
    o += w * (float)Op[(size_t)s * SEQ * DH + idx];
  }
  out[idx] = o / L;
}

extern "C" void kernel_launch(void* const* d_in, const int* in_sizes, int n_in,
                              void* d_out, int out_size, void* d_ws, size_t ws_size,
                              hipStream_t stream) {
  const float* x = (const float*)d_in[0];
  const float* W = (const float*)d_in[1];
  const float* b = (const float*)d_in[2];
  float* out = (float*)d_out;
  char* ws = (char*)d_ws;

  f16*   Wh   = (f16*)(ws);                      // [0, 3M)
  f16*   qkv  = (f16*)(ws + (3u << 20));         // [3M, 6M)
  f16*   Vt   = (f16*)(ws + (6u << 20));         // [6M, 7M)
  float* ml   = (float*)(ws + (7u << 20));       // [7M, 7.5M)
  char*  scr  = ws + (7u << 20) + (1u << 19);    // gemm partials, later Op
  f16*   part = (f16*)scr;                       // 8 * 3MB
  f16*   Op   = (f16*)scr;                       // 16 MB (reuses partials region)

  cvt_w_kernel<<<(384 * 4096 / 4) / 256, 256, 0, stream>>>((const float4*)W, (f16x4*)Wh);

  bool big = ws_size >= ((size_t)31u << 20) + ((size_t)1u << 19);
  if (big) {
    gemm_qkv<8><<<dim3(SEQ / 64, 8), 256, 0, stream>>>(x, Wh, part);
    reduce_qkv<8><<<SEQ * QKV_LD / 8 / 256, 256, 0, stream>>>(part, b, qkv);
  } else {
    gemm_qkv<4><<<dim3(SEQ / 64, 4), 256, 0, stream>>>(x, Wh, part);
    reduce_qkv<4><<<SEQ * QKV_LD / 8 / 256, 256, 0, stream>>>(part, b, qkv);
  }
  transpose_v<<<dim3(SEQ / 64, DH / 64), 256, 0, stream>>>(qkv, Vt);
  attn_partial<<<dim3(SEQ / 128, NSPLIT), 256, 0, stream>>>(qkv, Vt, Op, ml);
  combine_kernel<<<(SEQ * DH) / 256, 256, 0, stream>>>(Op, ml, out);
}